// Round 2
// baseline (218.087 us; speedup 1.0000x reference)
//
#include <hip/hip_runtime.h>
#include <stdint.h>

// Problem constants (fixed by setup_inputs)
#define BATCH 32
#define CH    256
#define MID   64
#define HW    3136   // 56*56
#define HWV   784    // HW / 4 (float4 vectors per plane)

// Kernel 1: global average pool. One block per (b,c) plane of 3136 elems.
__global__ __launch_bounds__(256) void se_pool(const float4* __restrict__ x,
                                               float* __restrict__ pooled) {
    const int p = blockIdx.x;                 // plane index = b*CH + c
    const float4* base = x + (size_t)p * HWV;
    const int t = threadIdx.x;

    float sum = 0.0f;
    for (int i = t; i < HWV; i += 256) {
        float4 v = base[i];
        sum += v.x + v.y + v.z + v.w;
    }
    // wave (64-lane) reduction
    #pragma unroll
    for (int off = 32; off > 0; off >>= 1) sum += __shfl_down(sum, off, 64);

    __shared__ float part[4];
    if ((t & 63) == 0) part[t >> 6] = sum;
    __syncthreads();
    if (t == 0) {
        float s = part[0] + part[1] + part[2] + part[3];
        pooled[p] = s * (1.0f / (float)HW);
    }
}

// Kernel 2: squeeze-excite MLP: relu(pooled @ w1^T + b1) -> hsig(h @ w2^T + b2).
// One block per batch element. w1 is [MID, CH] row-major, w2 is [CH, MID].
__global__ __launch_bounds__(256) void se_gate(const float* __restrict__ pooled,
                                               const float* __restrict__ w1,
                                               const float* __restrict__ b1,
                                               const float* __restrict__ w2,
                                               const float* __restrict__ b2,
                                               float* __restrict__ gate) {
    const int b = blockIdx.x;
    const int t = threadIdx.x;

    __shared__ float ps[CH];
    __shared__ float hs[MID];

    ps[t] = pooled[b * CH + t];
    __syncthreads();

    if (t < MID) {
        float acc = b1[t];
        const float4* wrow = (const float4*)(w1 + t * CH);
        #pragma unroll 8
        for (int i = 0; i < CH / 4; ++i) {
            float4 wv = wrow[i];
            acc += ps[i * 4 + 0] * wv.x + ps[i * 4 + 1] * wv.y +
                   ps[i * 4 + 2] * wv.z + ps[i * 4 + 3] * wv.w;
        }
        hs[t] = fmaxf(acc, 0.0f);
    }
    __syncthreads();

    float acc = b2[t];
    const float4* wrow = (const float4*)(w2 + t * MID);
    #pragma unroll
    for (int i = 0; i < MID / 4; ++i) {
        float4 wv = wrow[i];
        acc += hs[i * 4 + 0] * wv.x + hs[i * 4 + 1] * wv.y +
               hs[i * 4 + 2] * wv.z + hs[i * 4 + 3] * wv.w;
    }
    float g = fminf(fmaxf(acc + 3.0f, 0.0f), 6.0f) * 0.16666667f;
    gate[b * CH + t] = g;
}

// Kernel 3: out = x * gate[b,c], one block per (b,c) plane.
__global__ __launch_bounds__(256) void se_scale(const float4* __restrict__ x,
                                                const float* __restrict__ gate,
                                                float4* __restrict__ out) {
    const int p = blockIdx.x;
    const float g = gate[p];
    const float4* xb = x + (size_t)p * HWV;
    float4* ob = out + (size_t)p * HWV;
    const int t = threadIdx.x;

    for (int i = t; i < HWV; i += 256) {
        float4 v = xb[i];
        float4 r;
        r.x = v.x * g; r.y = v.y * g; r.z = v.z * g; r.w = v.w * g;
        ob[i] = r;
    }
}

extern "C" void kernel_launch(void* const* d_in, const int* in_sizes, int n_in,
                              void* d_out, int out_size, void* d_ws, size_t ws_size,
                              hipStream_t stream) {
    (void)in_sizes; (void)n_in; (void)out_size; (void)ws_size;

    const float* x  = (const float*)d_in[0];
    const float* w1 = (const float*)d_in[1];
    const float* b1 = (const float*)d_in[2];
    const float* w2 = (const float*)d_in[3];
    const float* b2 = (const float*)d_in[4];

    float* pooled = (float*)d_ws;            // BATCH*CH floats = 32 KB
    float* gate   = pooled + BATCH * CH;     // BATCH*CH floats = 32 KB

    se_pool<<<BATCH * CH, 256, 0, stream>>>((const float4*)x, pooled);
    se_gate<<<BATCH, 256, 0, stream>>>(pooled, w1, b1, w2, b2, gate);
    se_scale<<<BATCH * CH, 256, 0, stream>>>((const float4*)x, gate, (float4*)d_out);
}